// Round 13
// baseline (632.492 us; speedup 1.0000x reference)
//
#include <hip/hip_runtime.h>

#define T_LEN 1024
#define M_DIM 128
#define B_NUM 64

typedef _Float16 h2 __attribute__((ext_vector_type(2)));

#if __has_builtin(__builtin_amdgcn_fdot2)
#define DOT2(a, b, c) __builtin_amdgcn_fdot2((a), (b), (c), false)
#else
__device__ __forceinline__ float DOT2(h2 a, h2 b, float c) {
  return fmaf((float)a.x, (float)b.x, fmaf((float)a.y, (float)b.y, c));
}
#endif

// ONE WAVE per batch (64 blocks x 64 thr) with FULL __syncthreads() per step
// and ZERO inline asm. r10's verified datapath (mapping re-audited); the only
// change vs r10 is the sync discipline: r8/r12 (same f16 math, absmax 0) used
// real barriers, r9/r10 (hand lgkmcnt, no barrier) corrupted u — so this
// round isolates ordering as the failure cause. For a 1-wave block s_barrier
// is ~free; its vmcnt(0) drain is amortized r4-style (8-row P burst/window).
// Lane l owns states j0=2l, j1=2l+1 (pair lane-local, ONE b32 write). W as
// four 32-elem h2 arrays (128 VGPR, static idx). Per step: 16 uniform
// ds_read_b128 broadcast u (256 B), 128 v_dot2_f32_f16, lag-1 Z renorm with
// 2^-8 headroom (stored max <= ~3.7e3 < 65504; self-consistent for ANY
// finite Z since the same Zreg divides u and adds to C). Z tree = proven
// __shfl_xor chain. Clamps scrub NaN/Inf -> failures stay finite/diagnosable.
__global__ __launch_bounds__(64, 1) void crf_fwd(
    const float* __restrict__ P, const float* __restrict__ A,
    const int* __restrict__ Y, const int* __restrict__ L,
    float* __restrict__ out)
{
  const int b  = blockIdx.x;
  const int l  = threadIdx.x;      // lane 0..63
  const int j0 = 2 * l;            // even state; odd partner = j0+1

  __shared__ __align__(16) h2 u_pk[2][64];   // pair m = states {2m, 2m+1}

  const int Lb = L[b];
  const float* Pb = P + (size_t)b * T_LEN * M_DIM;
  const int*   Yb = Y + b * T_LEN;

  // W pairs (r10 mapping, re-verified): wA*[m] -> column j0, wB*[m] -> j0+1;
  // pair m = rows {2m,2m+1} (A0/B0: rows 0..63; A1/B1: rows 64..127).
  h2 wA0[32], wB0[32], wA1[32], wB1[32];
  #pragma unroll
  for (int m = 0; m < 32; ++m) {
    float2 ra = *(const float2*)(A + (2 * m) * M_DIM + j0);
    float2 rb = *(const float2*)(A + (2 * m + 1) * M_DIM + j0);
    h2 a0; a0.x = (_Float16)__expf(ra.x); a0.y = (_Float16)__expf(rb.x);
    h2 b0; b0.x = (_Float16)__expf(ra.y); b0.y = (_Float16)__expf(rb.y);
    wA0[m] = a0; wB0[m] = b0;
    float2 rc = *(const float2*)(A + (64 + 2 * m) * M_DIM + j0);
    float2 rd = *(const float2*)(A + (64 + 2 * m + 1) * M_DIM + j0);
    h2 a1; a1.x = (_Float16)__expf(rc.x); a1.y = (_Float16)__expf(rd.x);
    h2 b1; b1.x = (_Float16)__expf(rc.y); b1.y = (_Float16)__expf(rd.y);
    wA1[m] = a1; wB1[m] = b1;
  }

  // ---- path score sY: no sequential dependency, gather wave-wide ----
  float sY = 0.f;
  for (int tt = l; tt < Lb; tt += 64) {
    int yt = Yb[tt];
    float term = Pb[tt * M_DIM + yt];
    term += (tt == 0) ? A[M_DIM * M_DIM + yt] : A[Yb[tt - 1] * M_DIM + yt];
    sY += term;
  }
  #pragma unroll
  for (int d = 1; d < 64; d <<= 1) sY += __shfl_xor(sY, d);

  // ---- t = 0: m0-normalize (stored max = 1.0 exactly) ----
  float2 pp = *(const float2*)(Pb + j0);
  float2 aa = *(const float2*)(A + M_DIM * M_DIM + j0);
  float s00 = pp.x + aa.x, s01 = pp.y + aa.y;
  float m0 = fmaxf(s00, s01);
  #pragma unroll
  for (int d = 1; d < 64; d <<= 1) m0 = fmaxf(m0, __shfl_xor(m0, d));
  float C = m0;
  float un0 = __expf(s00 - C);
  float un1 = __expf(s01 - C);
  float Zreg = 1.0f;
  {
    h2 hv; hv.x = (_Float16)un0; hv.y = (_Float16)un1;
    u_pk[0][l] = hv;
  }

  if (Lb == 1) {
    float zs = un0 + un1;
    #pragma unroll
    for (int d = 1; d < 64; d <<= 1) zs += __shfl_xor(zs, d);
    if (l == 0) out[b] = __logf(zs) + C - sY;
    return;
  }

  float2 p_cur = *(const float2*)(Pb + M_DIM + j0);   // row t=1
  int cur = 0;
  int tb  = 1;   // window handles steps tb..tb+7
  __syncthreads();   // u_pk[0] visible before first read

#define CRF_STEP(S, PN)                                                    \
  {                                                                        \
    float iZ  = __builtin_amdgcn_rcpf(Zreg) * 0.00390625f;                 \
    C += __logf(Zreg) + 5.54517744f;   /* log Z + 8 ln 2 */                \
    float ep0 = __expf(p_cur.x) * iZ;                                      \
    float ep1 = __expf(p_cur.y) * iZ;                                      \
    const float4* u4 = (const float4*)&u_pk[cur][0];                       \
    float a00 = 0.f, a01 = 0.f, a02 = 0.f, a03 = 0.f;                      \
    float a10 = 0.f, a11 = 0.f, a12 = 0.f, a13 = 0.f;                      \
    _Pragma("unroll")                                                      \
    for (int k = 0; k < 8; ++k) {                                          \
      float4 uu = u4[k];                                                   \
      h2 ux = __builtin_bit_cast(h2, uu.x);                                \
      h2 uy = __builtin_bit_cast(h2, uu.y);                                \
      h2 uz = __builtin_bit_cast(h2, uu.z);                                \
      h2 uw = __builtin_bit_cast(h2, uu.w);                                \
      a00 = DOT2(ux, wA0[4 * k + 0], a00);                                 \
      a10 = DOT2(ux, wB0[4 * k + 0], a10);                                 \
      a01 = DOT2(uy, wA0[4 * k + 1], a01);                                 \
      a11 = DOT2(uy, wB0[4 * k + 1], a11);                                 \
      a02 = DOT2(uz, wA0[4 * k + 2], a02);                                 \
      a12 = DOT2(uz, wB0[4 * k + 2], a12);                                 \
      a03 = DOT2(uw, wA0[4 * k + 3], a03);                                 \
      a13 = DOT2(uw, wB0[4 * k + 3], a13);                                 \
    }                                                                      \
    _Pragma("unroll")                                                      \
    for (int k = 0; k < 8; ++k) {                                          \
      float4 uu = u4[8 + k];                                               \
      h2 ux = __builtin_bit_cast(h2, uu.x);                                \
      h2 uy = __builtin_bit_cast(h2, uu.y);                                \
      h2 uz = __builtin_bit_cast(h2, uu.z);                                \
      h2 uw = __builtin_bit_cast(h2, uu.w);                                \
      a00 = DOT2(ux, wA1[4 * k + 0], a00);                                 \
      a10 = DOT2(ux, wB1[4 * k + 0], a10);                                 \
      a01 = DOT2(uy, wA1[4 * k + 1], a01);                                 \
      a11 = DOT2(uy, wB1[4 * k + 1], a11);                                 \
      a02 = DOT2(uz, wA1[4 * k + 2], a02);                                 \
      a12 = DOT2(uz, wB1[4 * k + 2], a12);                                 \
      a03 = DOT2(uw, wA1[4 * k + 3], a03);                                 \
      a13 = DOT2(uw, wB1[4 * k + 3], a13);                                 \
    }                                                                      \
    un0 = ((a00 + a01) + (a02 + a03)) * ep0;                               \
    un1 = ((a10 + a11) + (a12 + a13)) * ep1;                               \
    un0 = fminf(fmaxf(un0, 1e-35f), 60000.f);   /* NaN/Inf scrub */        \
    un1 = fminf(fmaxf(un1, 1e-35f), 60000.f);                              \
    {                                                                      \
      h2 hv; hv.x = (_Float16)un0; hv.y = (_Float16)un1;                   \
      u_pk[cur ^ 1][l] = hv;                                               \
    }                                                                      \
    { /* lag-1 Z: proven shfl_xor max chain (all lanes get global max) */  \
      float zm = fmaxf(un0, un1);                                          \
      _Pragma("unroll")                                                    \
      for (int d = 1; d < 64; d <<= 1) zm = fmaxf(zm, __shfl_xor(zm, d));  \
      Zreg = zm;                                                           \
    }                                                                      \
    if (tb + (S) == Lb - 1) goto finish;                                   \
    p_cur = (PN);                                                          \
    cur ^= 1;                                                              \
    __syncthreads();                                                       \
  }

  for (;;) {
    // Burst-prefetch P rows tb+1..tb+8 (clamped) once per window: the first
    // step-end barrier drains them (one amortized stall per 8 steps, r4-style).
    float2 q0, q1, q2, q3, q4, q5, q6, q7;
    {
      int r;
      r = tb + 1; r = r < T_LEN ? r : T_LEN - 1; q0 = *(const float2*)(Pb + r * M_DIM + j0);
      r = tb + 2; r = r < T_LEN ? r : T_LEN - 1; q1 = *(const float2*)(Pb + r * M_DIM + j0);
      r = tb + 3; r = r < T_LEN ? r : T_LEN - 1; q2 = *(const float2*)(Pb + r * M_DIM + j0);
      r = tb + 4; r = r < T_LEN ? r : T_LEN - 1; q3 = *(const float2*)(Pb + r * M_DIM + j0);
      r = tb + 5; r = r < T_LEN ? r : T_LEN - 1; q4 = *(const float2*)(Pb + r * M_DIM + j0);
      r = tb + 6; r = r < T_LEN ? r : T_LEN - 1; q5 = *(const float2*)(Pb + r * M_DIM + j0);
      r = tb + 7; r = r < T_LEN ? r : T_LEN - 1; q6 = *(const float2*)(Pb + r * M_DIM + j0);
      r = tb + 8; r = r < T_LEN ? r : T_LEN - 1; q7 = *(const float2*)(Pb + r * M_DIM + j0);
    }
    CRF_STEP(0, q0)
    CRF_STEP(1, q1)
    CRF_STEP(2, q2)
    CRF_STEP(3, q3)
    CRF_STEP(4, q4)
    CRF_STEP(5, q5)
    CRF_STEP(6, q6)
    CRF_STEP(7, q7)
    tb += 8;
  }

finish:
  {
    float zs = un0 + un1;
    #pragma unroll
    for (int d = 1; d < 64; d <<= 1) zs += __shfl_xor(zs, d);
    if (l == 0) out[b] = __logf(zs) + C - sY;
  }
}

extern "C" void kernel_launch(void* const* d_in, const int* in_sizes, int n_in,
                              void* d_out, int out_size, void* d_ws, size_t ws_size,
                              hipStream_t stream) {
  const float* P = (const float*)d_in[0];
  const float* A = (const float*)d_in[1];
  const int*   Y = (const int*)d_in[2];
  const int*   L = (const int*)d_in[3];
  float* o = (float*)d_out;
  hipLaunchKernelGGL(crf_fwd, dim3(B_NUM), dim3(64), 0, stream, P, A, Y, L, o);
}

// Round 14
// 505.409 us; speedup vs baseline: 1.2514x; 1.2514x over previous
//
#include <hip/hip_runtime.h>

#define T_LEN 1024
#define M_DIM 128
#define B_NUM 64

typedef _Float16 h2 __attribute__((ext_vector_type(2)));

#if __has_builtin(__builtin_amdgcn_fdot2)
#define DOT2(a, b, c) __builtin_amdgcn_fdot2((a), (b), (c), false)
#else
__device__ __forceinline__ float DOT2(h2 a, h2 b, float c) {
  return fmaf((float)a.x, (float)b.x, fmaf((float)a.y, (float)b.y, c));
}
#endif

// DPP lane-max (VALU pipe). bound_ctrl=true (invalid lanes read 0; operands
// nonneg so fmax is unaffected). Ctrls verified in r12 (passed, absmax 0).
template<int CTRL>
__device__ __forceinline__ float dppmax(float x) {
  int y = __builtin_amdgcn_update_dpp(0, __float_as_int(x), CTRL, 0xf, 0xf, true);
  return fmaxf(x, __int_as_float(y));
}

__device__ __forceinline__ unsigned pack_f16(float a, float bq) {
  h2 hv; hv.x = (_Float16)a; hv.y = (_Float16)bq;   // RTE, matches r8/r13
  return __builtin_bit_cast(unsigned, hv);
}

// ONE WAVE per batch, REGISTERS ONLY in the time loop: no LDS, no barriers,
// no DS ops. Lane l owns states j0=2l, j1=2l+1; per step it packs {un0,un1}
// into one VGPR and 64 v_readlane_b32 (constant lane idx, exec-agnostic)
// broadcast every pair to all lanes; 128 v_dot2_f32_f16 against the r13-
// proven W layout (four 32-elem h2 arrays, VGPR-resident at 172 regs).
// r13 post-mortem: its 1490 cyc/step = shfl_xor Z-chain (6 dependent
// ds_bpermute, ~500 cyc) forced onto the critical path by __syncthreads'
// lgkmcnt(0) drain + LDS round-trip latency, with zero co-resident waves to
// hide any of it. This version's step is pure VALU issue (~223 instr).
// Z: lag-1 via the r12-proven DPP tree + readlane(16/48); consumed at the
// NEXT step's end (ep multiply) -> off the critical chain. Numerics
// identical to r13 (absmax 0): 2^-8 headroom, self-consistent for any
// finite Z (same Zreg divides u and adds to C). Clamps scrub NaN/Inf.
__global__ __launch_bounds__(64, 1) void crf_fwd(
    const float* __restrict__ P, const float* __restrict__ A,
    const int* __restrict__ Y, const int* __restrict__ L,
    float* __restrict__ out)
{
  const int b  = blockIdx.x;
  const int l  = threadIdx.x;      // lane 0..63
  const int j0 = 2 * l;            // even state; odd partner = j0+1

  const int Lb = L[b];
  const float* Pb = P + (size_t)b * T_LEN * M_DIM;
  const int*   Yb = Y + b * T_LEN;

  // W pairs (r13 mapping, verified absmax 0): wA*[m] -> column j0,
  // wB*[m] -> j0+1; pair m = rows {2m,2m+1}. 32-elem arrays stay in VGPRs.
  h2 wA0[32], wB0[32], wA1[32], wB1[32];
  #pragma unroll
  for (int m = 0; m < 32; ++m) {
    float2 ra = *(const float2*)(A + (2 * m) * M_DIM + j0);
    float2 rb = *(const float2*)(A + (2 * m + 1) * M_DIM + j0);
    h2 a0; a0.x = (_Float16)__expf(ra.x); a0.y = (_Float16)__expf(rb.x);
    h2 b0; b0.x = (_Float16)__expf(ra.y); b0.y = (_Float16)__expf(rb.y);
    wA0[m] = a0; wB0[m] = b0;
    float2 rc = *(const float2*)(A + (64 + 2 * m) * M_DIM + j0);
    float2 rd = *(const float2*)(A + (64 + 2 * m + 1) * M_DIM + j0);
    h2 a1; a1.x = (_Float16)__expf(rc.x); a1.y = (_Float16)__expf(rd.x);
    h2 b1; b1.x = (_Float16)__expf(rc.y); b1.y = (_Float16)__expf(rd.y);
    wA1[m] = a1; wB1[m] = b1;
  }

  // ---- path score sY: no sequential dependency, gather wave-wide ----
  float sY = 0.f;
  for (int tt = l; tt < Lb; tt += 64) {
    int yt = Yb[tt];
    float term = Pb[tt * M_DIM + yt];
    term += (tt == 0) ? A[M_DIM * M_DIM + yt] : A[Yb[tt - 1] * M_DIM + yt];
    sY += term;
  }
  #pragma unroll
  for (int d = 1; d < 64; d <<= 1) sY += __shfl_xor(sY, d);

  // ---- t = 0: m0-normalize (stored max = 1.0 exactly) ----
  float2 pp = *(const float2*)(Pb + j0);
  float2 aa = *(const float2*)(A + M_DIM * M_DIM + j0);
  float s00 = pp.x + aa.x, s01 = pp.y + aa.y;
  float m0 = fmaxf(s00, s01);
  #pragma unroll
  for (int d = 1; d < 64; d <<= 1) m0 = fmaxf(m0, __shfl_xor(m0, d));
  float C = m0;
  float un0 = __expf(s00 - C);
  float un1 = __expf(s01 - C);
  float Zreg = 1.0f;

  if (Lb == 1) {
    float zs = un0 + un1;
    #pragma unroll
    for (int d = 1; d < 64; d <<= 1) zs += __shfl_xor(zs, d);
    if (l == 0) out[b] = __logf(zs) + C - sY;
    return;
  }

  float2 p_cur = *(const float2*)(Pb + M_DIM + j0);   // row t=1
  int tb = 1;   // window handles steps tb..tb+7

#define CRF_STEP(S, PN)                                                    \
  {                                                                        \
    float iZ  = __builtin_amdgcn_rcpf(Zreg) * 0.00390625f;                 \
    C += __logf(Zreg) + 5.54517744f;   /* log Z + 8 ln 2 */                \
    float ep0 = __expf(p_cur.x) * iZ;                                      \
    float ep1 = __expf(p_cur.y) * iZ;                                      \
    const unsigned upk = pack_f16(un0, un1);                               \
    float a00 = 0.f, a01 = 0.f, a02 = 0.f, a03 = 0.f;                      \
    float b00 = 0.f, b01 = 0.f, b02 = 0.f, b03 = 0.f;                      \
    _Pragma("unroll")                                                      \
    for (int k = 0; k < 32; k += 4) {                                      \
      h2 u0 = __builtin_bit_cast(h2, __builtin_amdgcn_readlane(upk, k));   \
      h2 u1 = __builtin_bit_cast(h2, __builtin_amdgcn_readlane(upk, k+1)); \
      h2 u2 = __builtin_bit_cast(h2, __builtin_amdgcn_readlane(upk, k+2)); \
      h2 u3 = __builtin_bit_cast(h2, __builtin_amdgcn_readlane(upk, k+3)); \
      a00 = DOT2(u0, wA0[k],     a00);  b00 = DOT2(u0, wB0[k],     b00);   \
      a01 = DOT2(u1, wA0[k + 1], a01);  b01 = DOT2(u1, wB0[k + 1], b01);   \
      a02 = DOT2(u2, wA0[k + 2], a02);  b02 = DOT2(u2, wB0[k + 2], b02);   \
      a03 = DOT2(u3, wA0[k + 3], a03);  b03 = DOT2(u3, wB0[k + 3], b03);   \
    }                                                                      \
    _Pragma("unroll")                                                      \
    for (int k = 0; k < 32; k += 4) {                                      \
      h2 u0 = __builtin_bit_cast(h2, __builtin_amdgcn_readlane(upk, 32+k));   \
      h2 u1 = __builtin_bit_cast(h2, __builtin_amdgcn_readlane(upk, 33+k));   \
      h2 u2 = __builtin_bit_cast(h2, __builtin_amdgcn_readlane(upk, 34+k));   \
      h2 u3 = __builtin_bit_cast(h2, __builtin_amdgcn_readlane(upk, 35+k));   \
      a00 = DOT2(u0, wA1[k],     a00);  b00 = DOT2(u0, wB1[k],     b00);   \
      a01 = DOT2(u1, wA1[k + 1], a01);  b01 = DOT2(u1, wB1[k + 1], b01);   \
      a02 = DOT2(u2, wA1[k + 2], a02);  b02 = DOT2(u2, wB1[k + 2], b02);   \
      a03 = DOT2(u3, wA1[k + 3], a03);  b03 = DOT2(u3, wB1[k + 3], b03);   \
    }                                                                      \
    un0 = ((a00 + a01) + (a02 + a03)) * ep0;                               \
    un1 = ((b00 + b01) + (b02 + b03)) * ep1;                               \
    un0 = fminf(fmaxf(un0, 1e-35f), 60000.f);   /* NaN/Inf scrub */        \
    un1 = fminf(fmaxf(un1, 1e-35f), 60000.f);                              \
    { /* lag-1 Z: r12-proven DPP tree, consumed next step -> hidden */     \
      float zm = fmaxf(un0, un1);                                          \
      zm = dppmax<0xB1>(zm);     /* quad xor1 */                           \
      zm = dppmax<0x4E>(zm);     /* quad xor2 */                           \
      zm = dppmax<0x141>(zm);    /* half-mirror -> 8-uniform */            \
      zm = dppmax<0x140>(zm);    /* mirror -> 16-uniform */                \
      zm = dppmax<0x142>(zm);    /* lane16=max(r0,r1), lane48=max(r2,r3) */\
      float za = __builtin_bit_cast(float, __builtin_amdgcn_readlane(      \
                     __builtin_bit_cast(int, zm), 16));                    \
      float zb = __builtin_bit_cast(float, __builtin_amdgcn_readlane(      \
                     __builtin_bit_cast(int, zm), 48));                    \
      Zreg = fmaxf(za, zb);                                                \
    }                                                                      \
    if (tb + (S) == Lb - 1) goto finish;                                   \
    p_cur = (PN);                                                          \
  }

  for (;;) {
    // Burst-prefetch P rows tb+1..tb+8 (clamped); no barriers exist, so
    // these are never force-drained — consumed with counted vmcnt.
    float2 q0, q1, q2, q3, q4, q5, q6, q7;
    {
      int r;
      r = tb + 1; r = r < T_LEN ? r : T_LEN - 1; q0 = *(const float2*)(Pb + r * M_DIM + j0);
      r = tb + 2; r = r < T_LEN ? r : T_LEN - 1; q1 = *(const float2*)(Pb + r * M_DIM + j0);
      r = tb + 3; r = r < T_LEN ? r : T_LEN - 1; q2 = *(const float2*)(Pb + r * M_DIM + j0);
      r = tb + 4; r = r < T_LEN ? r : T_LEN - 1; q3 = *(const float2*)(Pb + r * M_DIM + j0);
      r = tb + 5; r = r < T_LEN ? r : T_LEN - 1; q4 = *(const float2*)(Pb + r * M_DIM + j0);
      r = tb + 6; r = r < T_LEN ? r : T_LEN - 1; q5 = *(const float2*)(Pb + r * M_DIM + j0);
      r = tb + 7; r = r < T_LEN ? r : T_LEN - 1; q6 = *(const float2*)(Pb + r * M_DIM + j0);
      r = tb + 8; r = r < T_LEN ? r : T_LEN - 1; q7 = *(const float2*)(Pb + r * M_DIM + j0);
    }
    CRF_STEP(0, q0)
    CRF_STEP(1, q1)
    CRF_STEP(2, q2)
    CRF_STEP(3, q3)
    CRF_STEP(4, q4)
    CRF_STEP(5, q5)
    CRF_STEP(6, q6)
    CRF_STEP(7, q7)
    tb += 8;
  }

finish:
  {
    float zs = un0 + un1;
    #pragma unroll
    for (int d = 1; d < 64; d <<= 1) zs += __shfl_xor(zs, d);
    if (l == 0) out[b] = __logf(zs) + C - sY;
  }
}

extern "C" void kernel_launch(void* const* d_in, const int* in_sizes, int n_in,
                              void* d_out, int out_size, void* d_ws, size_t ws_size,
                              hipStream_t stream) {
  const float* P = (const float*)d_in[0];
  const float* A = (const float*)d_in[1];
  const int*   Y = (const int*)d_in[2];
  const int*   L = (const int*)d_in[3];
  float* o = (float*)d_out;
  hipLaunchKernelGGL(crf_fwd, dim3(B_NUM), dim3(64), 0, stream, P, A, Y, L, o);
}